// Round 13
// baseline (4675.846 us; speedup 1.0000x reference)
//
#include <hip/hip_runtime.h>
#include <math.h>

#define BATCH 512
#define TT    1024
#define FF    128
#define UU    50
#define ZN    200            // 4*UU
#define NP    208            // padded N (13*16)
#define NTL   13             // N tiles of 16
#define CH    32             // timesteps per chunk/tile
#define NCH   32             // TT/CH
#define NTILE (BATCH * NCH)  // 16384 producer tiles
#define NPROD 1536           // producer blocks (1 wave each)
#define RPP   8

typedef __attribute__((ext_vector_type(8))) short bhalf8;
typedef __attribute__((ext_vector_type(4))) float f32x4;
typedef __attribute__((ext_vector_type(2))) float f32x2;

__device__ __forceinline__ float rcp_fast(float x) { return __builtin_amdgcn_rcpf(x); }
__device__ __forceinline__ float sigmoid_fast(float x) {
    return rcp_fast(1.0f + __builtin_amdgcn_exp2f(-1.442695041f * x));
}
__device__ __forceinline__ float tanh_fast(float x) {
    float e = __builtin_amdgcn_exp2f(2.885390082f * x);
    return fmaf(-2.0f, rcp_fast(e + 1.0f), 1.0f);
}
__device__ __forceinline__ unsigned short bf16_rtn(float x) {
    unsigned int u = __float_as_uint(x);
    unsigned int r = u + 0x7FFFu + ((u >> 16) & 1u);
    return (unsigned short)(r >> 16);
}
__device__ __forceinline__ float bf16_f32(unsigned short h) {
    return __uint_as_float(((unsigned int)h) << 16);
}
__device__ __forceinline__ void cvt8(const float4 a, const float4 b,
                                     bhalf8& hi, bhalf8& lo) {
    float v0 = a.x, v1 = a.y, v2 = a.z, v3 = a.w;
    float v4 = b.x, v5 = b.y, v6 = b.z, v7 = b.w;
    unsigned short h0 = bf16_rtn(v0), h1 = bf16_rtn(v1), h2 = bf16_rtn(v2), h3 = bf16_rtn(v3);
    unsigned short h4 = bf16_rtn(v4), h5 = bf16_rtn(v5), h6 = bf16_rtn(v6), h7 = bf16_rtn(v7);
    hi[0]=(short)h0; hi[1]=(short)h1; hi[2]=(short)h2; hi[3]=(short)h3;
    hi[4]=(short)h4; hi[5]=(short)h5; hi[6]=(short)h6; hi[7]=(short)h7;
    lo[0]=(short)bf16_rtn(v0 - bf16_f32(h0)); lo[1]=(short)bf16_rtn(v1 - bf16_f32(h1));
    lo[2]=(short)bf16_rtn(v2 - bf16_f32(h2)); lo[3]=(short)bf16_rtn(v3 - bf16_f32(h3));
    lo[4]=(short)bf16_rtn(v4 - bf16_f32(h4)); lo[5]=(short)bf16_rtn(v5 - bf16_f32(h5));
    lo[6]=(short)bf16_rtn(v6 - bf16_f32(h6)); lo[7]=(short)bf16_rtn(v7 - bf16_f32(h7));
}

// ---------------- Prep: Kt_hi/Kt_lo[NP][FF] bf16 (transposed, hi/lo split) -------
__global__ void prep_kt_kernel(const float* __restrict__ K,
                               unsigned short* __restrict__ kt_hi,
                               unsigned short* __restrict__ kt_lo) {
    const int c = threadIdx.x;
    if (c >= NP) return;
    for (int k = 0; k < FF; ++k) {
        float v = (c < ZN) ? K[k * ZN + c] : 0.0f;
        unsigned short h = bf16_rtn(v);
        float lo = v - bf16_f32(h);
        kt_hi[c * FF + k] = h;
        kt_lo[c * FF + k] = bf16_rtn(lo);
    }
}

__global__ void zero_flags_kernel(int* __restrict__ flags) {
    const int i = blockIdx.x * 256 + threadIdx.x;
    if (i < NTILE) flags[i] = 0;
}

// ---------------- Mega kernel: block-role split producer/consumer ----------------
// Blocks 0..511: r10 scan of batch b (bit-identical step math), gated per chunk on
// device-scope flags. Blocks 512..2047: 1-wave producers grid-striding 16384
// (chunk-major) tiles: MFMA x@K+bias -> permuted zx[m][u*4+g], then release-flag.
// Producers never wait on consumers -> deadlock-free for ANY dispatch/residency
// order (worst case = serialization, i.e. r10 performance).
#define STEPF(V) do {                                                         \
    f32x2 acc0 = {(V).x, 0.f}, acc1 = {(V).y, 0.f};                           \
    f32x2 acc2 = {(V).z, 0.f}, acc3 = {(V).w, 0.f};                           \
    _Pragma("unroll")                                                         \
    for (int k4 = 0; k4 < 12; ++k4) {                                         \
        float4 hv = ((const float4*)hbuf)[k4];   /* uniform-addr broadcast */ \
        f32x2 hp0 = {hv.x, hv.y}, hp1 = {hv.z, hv.w};                         \
        acc0 = __builtin_elementwise_fma(hp0, rr0[2 * k4], acc0);             \
        acc1 = __builtin_elementwise_fma(hp0, rr1[2 * k4], acc1);             \
        acc2 = __builtin_elementwise_fma(hp0, rr2[2 * k4], acc2);             \
        acc3 = __builtin_elementwise_fma(hp0, rr3[2 * k4], acc3);             \
        acc0 = __builtin_elementwise_fma(hp1, rr0[2 * k4 + 1], acc0);         \
        acc1 = __builtin_elementwise_fma(hp1, rr1[2 * k4 + 1], acc1);         \
        acc2 = __builtin_elementwise_fma(hp1, rr2[2 * k4 + 1], acc2);         \
        acc3 = __builtin_elementwise_fma(hp1, rr3[2 * k4 + 1], acc3);         \
    }                                                                         \
    {                                                                         \
        f32x2 hp = ((const f32x2*)hbuf)[24];     /* h[48], h[49] */           \
        acc0 = __builtin_elementwise_fma(hp, rr0[24], acc0);                  \
        acc1 = __builtin_elementwise_fma(hp, rr1[24], acc1);                  \
        acc2 = __builtin_elementwise_fma(hp, rr2[24], acc2);                  \
        acc3 = __builtin_elementwise_fma(hp, rr3[24], acc3);                  \
    }                                                                         \
    float zi = acc0.x + acc0.y, zf = acc1.x + acc1.y;                         \
    float zg = acc2.x + acc2.y, zo = acc3.x + acc3.y;                         \
    float gi = sigmoid_fast(zi), gf = sigmoid_fast(zf);                       \
    float go = sigmoid_fast(zo), gg = tanh_fast(zg);                          \
    c = gf * c + gi * gg;                                                     \
    h = go * tanh_fast(c);                                                    \
    hbuf[l] = h;                                    /* lanes>=50 unread */    \
} while (0)

#define ISSUE4(DST, T0) do {                                                  \
    _Pragma("unroll")                                                         \
    for (int s = 0; s < 4; ++s) {                                             \
        int tt = (T0) + s; if (tt > TT - 1) tt = TT - 1;                      \
        if (act) DST[s] = *(const float4*)&zp[(size_t)tt * ZN + (l << 2)];    \
    }                                                                         \
} while (0)

#define STEPS4(SRC) do { STEPF(SRC[0]); STEPF(SRC[1]); STEPF(SRC[2]); STEPF(SRC[3]); } while (0)

#define WAITFLAG(C) do {                                                      \
    if (flags) {                                                              \
        const int* fp_ = flags + (C) * BATCH + b;                             \
        while (__hip_atomic_load(fp_, __ATOMIC_ACQUIRE,                       \
                                 __HIP_MEMORY_SCOPE_AGENT) == 0)              \
            __builtin_amdgcn_s_sleep(2);                                      \
    }                                                                         \
} while (0)

__launch_bounds__(64, 1)
__global__ void lstm_mega_kernel(const float* __restrict__ x,
                                 const unsigned short* __restrict__ kt_hi,
                                 const unsigned short* __restrict__ kt_lo,
                                 const float* __restrict__ bias,
                                 const float* __restrict__ R,
                                 const float* __restrict__ dw,
                                 const float* __restrict__ db,
                                 float* __restrict__ zx,
                                 int* __restrict__ flags,
                                 float* __restrict__ out) {
    __shared__ __align__(16) float hbuf[64];
    const int bid = blockIdx.x;
    const int l = threadIdx.x;

    if (bid >= BATCH) {
        // =================== PRODUCER (1 wave): grid-stride tiles ===================
        const int lrow = l & 15;
        const int lk   = (l >> 4) << 3;
        const int rsub = (l >> 4) << 2;

        float bvv[NTL];
        #pragma unroll
        for (int nt = 0; nt < NTL; ++nt) {
            const int j = nt * 16 + lrow;
            bvv[nt] = (j < ZN) ? bias[j] : 0.0f;
        }

        for (int i = bid - BATCH; i < NTILE; i += NPROD) {   // chunk-major order
            const int cc = i >> 9;           // chunk 0..31
            const int bb = i & (BATCH - 1);  // batch
            const size_t rowbase = (size_t)bb * TT + (size_t)cc * CH;

            #pragma unroll
            for (int mt = 0; mt < 2; ++mt) {
                f32x4 acc[NTL];
                #pragma unroll
                for (int nt = 0; nt < NTL; ++nt) acc[nt] = (f32x4)0.0f;
                #pragma unroll
                for (int kc = 0; kc < 4; ++kc) {
                    const float* xr = x + (rowbase + mt * 16 + lrow) * FF + kc * 32 + lk;
                    float4 a0 = *(const float4*)xr;
                    float4 a1 = *(const float4*)(xr + 4);
                    bhalf8 aH, aL;
                    cvt8(a0, a1, aH, aL);
                    #pragma unroll
                    for (int nt = 0; nt < NTL; ++nt) {
                        const size_t ko = (size_t)(nt * 16 + lrow) * FF + kc * 32 + lk;
                        bhalf8 bH = *(const bhalf8*)(kt_hi + ko);
                        bhalf8 bL = *(const bhalf8*)(kt_lo + ko);
                        acc[nt] = __builtin_amdgcn_mfma_f32_16x16x32_bf16(aH, bH, acc[nt], 0, 0, 0);
                        acc[nt] = __builtin_amdgcn_mfma_f32_16x16x32_bf16(aH, bL, acc[nt], 0, 0, 0);
                        acc[nt] = __builtin_amdgcn_mfma_f32_16x16x32_bf16(aL, bH, acc[nt], 0, 0, 0);
                    }
                }
                // D layout col=l&15, row=(l>>4)*4+r (verified r3+); permuted scatter
                // store zx[m][u*4+g] (4B stores; L2 write-back merges lines).
                #pragma unroll
                for (int nt = 0; nt < NTL; ++nt) {
                    const int j = nt * 16 + lrow;
                    if (j < ZN) {
                        const int pj = (j % UU) * 4 + j / UU;
                        #pragma unroll
                        for (int r = 0; r < 4; ++r)
                            zx[(rowbase + mt * 16 + rsub + r) * ZN + pj] = acc[nt][r] + bvv[nt];
                    }
                }
            }
            __threadfence();
            if (l == 0)
                __hip_atomic_store(&flags[i], 1, __ATOMIC_RELEASE, __HIP_MEMORY_SCOPE_AGENT);
        }
        return;
    }

    // ======================= CONSUMER: r10 scan of batch b =======================
    const int b = bid;
    const bool act = (l < UU);

    f32x2 rr0[25], rr1[25], rr2[25], rr3[25];
    #pragma unroll
    for (int p = 0; p < 25; ++p) {
        if (act) {
            rr0[p] = (f32x2){ R[(2*p) * ZN + l],       R[(2*p+1) * ZN + l] };
            rr1[p] = (f32x2){ R[(2*p) * ZN + l + 50],  R[(2*p+1) * ZN + l + 50] };
            rr2[p] = (f32x2){ R[(2*p) * ZN + l + 100], R[(2*p+1) * ZN + l + 100] };
            rr3[p] = (f32x2){ R[(2*p) * ZN + l + 150], R[(2*p+1) * ZN + l + 150] };
        } else {
            rr0[p] = (f32x2){0.f, 0.f}; rr1[p] = (f32x2){0.f, 0.f};
            rr2[p] = (f32x2){0.f, 0.f}; rr3[p] = (f32x2){0.f, 0.f};
        }
    }
    #pragma unroll
    for (int p = 0; p < 25; ++p)
        asm volatile("" : "+v"(rr0[p]), "+v"(rr1[p]), "+v"(rr2[p]), "+v"(rr3[p]));

    const float dwv = act ? dw[l] : 0.0f;
    const float* zp = zx + (size_t)b * TT * ZN;

    hbuf[l] = 0.0f;
    float h = 0.0f, c = 0.0f;

    float4 pf[4], qf[4];
    #pragma unroll
    for (int s = 0; s < 4; ++s) { pf[s] = (float4){0,0,0,0}; qf[s] = (float4){0,0,0,0}; }

    WAITFLAG(0);
    ISSUE4(pf, 0);
    for (int ch = 0; ch < NCH; ++ch) {
        if (ch < NCH - 1) WAITFLAG(ch + 1);   // covers all prefetch into chunk ch+1
        #pragma unroll 1
        for (int g = 0; g < 4; ++g) {
            const int t = ch * CH + g * 8;
            ISSUE4(qf, t + 4);
            STEPS4(pf);                       // steps t .. t+3
            ISSUE4(pf, t + 8);                // clamped (dead) at the very end
            STEPS4(qf);                       // steps t+4 .. t+7
        }
    }

    float s = act ? h * dwv : 0.0f;
    #pragma unroll
    for (int off = 32; off > 0; off >>= 1) s += __shfl_down(s, off, 64);
    if (l == 0) out[b] = s + db[0];
}

// ---------------- Fallback GEMM (r8-style, permuted store) -----------------------
__launch_bounds__(256, 1)
__global__ void xk_gemm_kernel(const float* __restrict__ x,
                               const float* __restrict__ K,
                               const float* __restrict__ bias,
                               float* __restrict__ zx) {
    const int b = blockIdx.x;
    const int j = threadIdx.x;

    __shared__ __align__(16) float xs[2][RPP * FF];

    float kreg[FF];
    float bj = 0.0f;
    if (j < ZN) {
        #pragma unroll
        for (int k = 0; k < FF; ++k) kreg[k] = K[k * ZN + j];
        bj = bias[j];
    }
    const int jpos = (j % UU) * 4 + (j / UU);

    const float* xrow = x + (size_t)b * TT * FF;
    float* zrow = zx + (size_t)b * TT * ZN;

    ((float4*)xs[0])[threadIdx.x] = ((const float4*)xrow)[threadIdx.x];
    __syncthreads();

    const int NPASS = TT / RPP;
    for (int p = 0; p < NPASS; ++p) {
        const int cur = p & 1, nxt = cur ^ 1;
        float4 gxv;
        const bool more = (p + 1) < NPASS;
        if (more) gxv = ((const float4*)(xrow + (size_t)(p + 1) * RPP * FF))[threadIdx.x];

        if (j < ZN) {
            float acc[RPP];
            #pragma unroll
            for (int r = 0; r < RPP; ++r) acc[r] = bj;
            const float4* xb4 = (const float4*)xs[cur];
            #pragma unroll
            for (int k4 = 0; k4 < FF / 4; ++k4) {
                #pragma unroll
                for (int r = 0; r < RPP; ++r) {
                    float4 xv = xb4[r * (FF / 4) + k4];
                    acc[r] = fmaf(xv.x, kreg[4 * k4 + 0], acc[r]);
                    acc[r] = fmaf(xv.y, kreg[4 * k4 + 1], acc[r]);
                    acc[r] = fmaf(xv.z, kreg[4 * k4 + 2], acc[r]);
                    acc[r] = fmaf(xv.w, kreg[4 * k4 + 3], acc[r]);
                }
            }
            float* zpo = zrow + (size_t)p * RPP * ZN + jpos;
            #pragma unroll
            for (int r = 0; r < RPP; ++r) zpo[r * ZN] = acc[r];
        }
        if (more) ((float4*)xs[nxt])[threadIdx.x] = gxv;
        __syncthreads();
    }
}

extern "C" void kernel_launch(void* const* d_in, const int* in_sizes, int n_in,
                              void* d_out, int out_size, void* d_ws, size_t ws_size,
                              hipStream_t stream) {
    const float* x    = (const float*)d_in[0];  // [512,1024,128]
    const float* K    = (const float*)d_in[1];  // [128,200]
    const float* R    = (const float*)d_in[2];  // [50,200]
    const float* bias = (const float*)d_in[3];  // [200]
    const float* dw   = (const float*)d_in[4];  // [50,1]
    const float* db   = (const float*)d_in[5];  // [1]
    float* out = (float*)d_out;                 // [512,1]

    const size_t zx_bytes  = (size_t)BATCH * TT * ZN * sizeof(float);   // 419.43 MB
    const size_t kt_elems  = (size_t)NP * FF;                           // 26624
    const size_t kt_bytes  = kt_elems * sizeof(unsigned short);
    const size_t flg_bytes = (size_t)NTILE * sizeof(int);               // 64 KB

    float* zx = (float*)d_ws;
    unsigned short* kt_hi = (unsigned short*)((char*)d_ws + zx_bytes);
    unsigned short* kt_lo = kt_hi + kt_elems;
    int* flags = (int*)((char*)d_ws + zx_bytes + 2 * kt_bytes);

    if (ws_size >= zx_bytes + 2 * kt_bytes + flg_bytes) {
        // fused pipeline: producers + flag-gated scan in one launch
        zero_flags_kernel<<<(NTILE + 255) / 256, 256, 0, stream>>>(flags);
        prep_kt_kernel<<<1, 256, 0, stream>>>(K, kt_hi, kt_lo);
        lstm_mega_kernel<<<BATCH + NPROD, 64, 0, stream>>>(
            x, kt_hi, kt_lo, bias, R, dw, db, zx, flags, out);
    } else {
        // fallback: sequential GEMM then scan (flags=nullptr -> no waits)
        xk_gemm_kernel<<<BATCH, 256, 0, stream>>>(x, K, bias, zx);
        lstm_mega_kernel<<<BATCH, 64, 0, stream>>>(
            x, nullptr, nullptr, bias, R, dw, db, zx, nullptr, out);
    }
}

// Round 14
// 735.741 us; speedup vs baseline: 6.3553x; 6.3553x over previous
//
#include <hip/hip_runtime.h>
#include <math.h>

#define BATCH 512
#define TT    1024
#define FF    128
#define UU    50
#define ZN    200          // 4*UU
#define NP    208          // padded N (13 * 16)
#define NTL   13           // N tiles of 16
#define MROWS (BATCH * TT) // 524288
#define BM    128          // rows per GEMM block
#define RPP   8            // rows per pass in fallback GEMM
#define ESTRIDE 212        // GEMM epilogue LDS row stride

typedef __attribute__((ext_vector_type(8))) short bhalf8;
typedef __attribute__((ext_vector_type(4))) short bhalf4;
typedef __attribute__((ext_vector_type(4))) float f32x4;
typedef __attribute__((ext_vector_type(2))) float f32x2;

__device__ __forceinline__ float rcp_fast(float x) { return __builtin_amdgcn_rcpf(x); }
__device__ __forceinline__ float sigmoid_fast(float x) {
    return rcp_fast(1.0f + __builtin_amdgcn_exp2f(-1.442695041f * x));
}
__device__ __forceinline__ float tanh_fast(float x) {
    float e = __builtin_amdgcn_exp2f(2.885390082f * x);
    return fmaf(-2.0f, rcp_fast(e + 1.0f), 1.0f);
}
__device__ __forceinline__ unsigned short bf16_rtn(float x) {
    unsigned int u = __float_as_uint(x);
    unsigned int r = u + 0x7FFFu + ((u >> 16) & 1u);
    return (unsigned short)(r >> 16);
}
__device__ __forceinline__ float bf16_f32(unsigned short h) {
    return __uint_as_float(((unsigned int)h) << 16);
}
// truncation split: hi = upper 16 bits, lo = trunc(x - hi). ~2 ops/elem vs ~8 for
// rtn-based; combined residual ~2^-16 rel (absmax headroom 170x at threshold).
__device__ __forceinline__ unsigned short bf16_tr(float x) {
    return (unsigned short)(__float_as_uint(x) >> 16);
}

// ---------------- Prep: Kt_hi/Kt_lo[NP][FF] bf16 — PARALLEL (104 blocks) ---------
__global__ void prep_kt_kernel(const float* __restrict__ K,
                               unsigned short* __restrict__ kt_hi,
                               unsigned short* __restrict__ kt_lo) {
    const int idx = blockIdx.x * 256 + threadIdx.x;   // (c,k) element
    if (idx >= NP * FF) return;
    const int c = idx / FF;
    const int k = idx - c * FF;
    float v = (c < ZN) ? K[k * ZN + c] : 0.0f;
    unsigned short h = bf16_rtn(v);                   // rtn here: cost negligible
    kt_hi[idx] = h;
    kt_lo[idx] = bf16_rtn(v - bf16_f32(h));
}

// ---------------- Kernel A: zx = x @ K + bias via bf16x2-split MFMA --------------
// r10 structure; staging cvt switched to truncation split (fewer VALU ops).
// Permuted epilogue zx4[m][u*4+g] (verified).
__launch_bounds__(256, 2)
__global__ void xk_mfma_kernel(const float* __restrict__ x,
                               const unsigned short* __restrict__ kt_hi,
                               const unsigned short* __restrict__ kt_lo,
                               const float* __restrict__ bias,
                               float* __restrict__ zx) {
    __shared__ __align__(16) char xlds[2 * BM * FF * 2];   // 64 KiB; reused by epilogue

    const int tid = threadIdx.x;
    const size_t rowbase = (size_t)blockIdx.x * BM;
    const float* xb = x + rowbase * FF;

    const float4* gx = (const float4*)xb;
    #pragma unroll
    for (int i = 0; i < 16; ++i) {
        float4 v = gx[tid + 256 * i];
        const int fidx = (tid + 256 * i) * 4;
        const int row = fidx >> 7;
        const int col = fidx & 127;
        unsigned short h0 = bf16_tr(v.x), h1 = bf16_tr(v.y),
                       h2 = bf16_tr(v.z), h3 = bf16_tr(v.w);
        bhalf4 hv = { (short)h0, (short)h1, (short)h2, (short)h3 };
        bhalf4 lv = { (short)bf16_tr(v.x - bf16_f32(h0)),
                      (short)bf16_tr(v.y - bf16_f32(h1)),
                      (short)bf16_tr(v.z - bf16_f32(h2)),
                      (short)bf16_tr(v.w - bf16_f32(h3)) };
        const unsigned byte = (unsigned)((row << 8) + (col << 1)) ^ (((unsigned)row & 7u) << 4);
        *(bhalf4*)(xlds + byte)         = hv;
        *(bhalf4*)(xlds + 32768 + byte) = lv;
    }
    __syncthreads();

    const int w = tid >> 6, l = tid & 63;
    const int lrow = l & 15;
    const int lk   = (l >> 4) << 3;

    float bv[NTL];
    #pragma unroll
    for (int nt = 0; nt < NTL; ++nt) {
        const int cidx = nt * 16 + lrow;
        bv[nt] = (cidx < ZN) ? bias[cidx] : 0.0f;
    }

    f32x4 acc0[NTL], acc1[NTL];
    #pragma unroll
    for (int nt = 0; nt < NTL; ++nt) { acc0[nt] = (f32x4)0.0f; acc1[nt] = (f32x4)0.0f; }

    #pragma unroll
    for (int ks = 0; ks < 4; ++ks) {
        const int kbyte = (ks * 32 + lk) * 2;
        const int row0 = (w << 5) + lrow;
        const int row1 = row0 + 16;
        const unsigned b0 = (unsigned)((row0 << 8) + kbyte) ^ (((unsigned)row0 & 7u) << 4);
        const unsigned b1 = (unsigned)((row1 << 8) + kbyte) ^ (((unsigned)row1 & 7u) << 4);
        bhalf8 aH0 = *(const bhalf8*)(xlds + b0);
        bhalf8 aL0 = *(const bhalf8*)(xlds + 32768 + b0);
        bhalf8 aH1 = *(const bhalf8*)(xlds + b1);
        bhalf8 aL1 = *(const bhalf8*)(xlds + 32768 + b1);
        #pragma unroll
        for (int nt = 0; nt < NTL; ++nt) {
            const size_t koff = ((size_t)(nt * 16 + lrow) << 7) + (size_t)(ks * 32 + lk);
            bhalf8 bH = *(const bhalf8*)(kt_hi + koff);
            bhalf8 bL = *(const bhalf8*)(kt_lo + koff);
            acc0[nt] = __builtin_amdgcn_mfma_f32_16x16x32_bf16(aH0, bH, acc0[nt], 0, 0, 0);
            acc0[nt] = __builtin_amdgcn_mfma_f32_16x16x32_bf16(aH0, bL, acc0[nt], 0, 0, 0);
            acc0[nt] = __builtin_amdgcn_mfma_f32_16x16x32_bf16(aL0, bH, acc0[nt], 0, 0, 0);
            acc1[nt] = __builtin_amdgcn_mfma_f32_16x16x32_bf16(aH1, bH, acc1[nt], 0, 0, 0);
            acc1[nt] = __builtin_amdgcn_mfma_f32_16x16x32_bf16(aH1, bL, acc1[nt], 0, 0, 0);
            acc1[nt] = __builtin_amdgcn_mfma_f32_16x16x32_bf16(aL1, bH, acc1[nt], 0, 0, 0);
        }
    }

    float* elds = (float*)xlds;
    const int rsub = (l >> 4) << 2;
    #pragma unroll
    for (int half = 0; half < 2; ++half) {
        __syncthreads();
        if ((w >> 1) == half) {
            const int lr = (w & 1) * 32;
            #pragma unroll
            for (int nt = 0; nt < NTL; ++nt) {
                #pragma unroll
                for (int r = 0; r < 4; ++r) {
                    elds[(lr + rsub + r) * ESTRIDE + nt * 16 + lrow]      = acc0[nt][r] + bv[nt];
                    elds[(lr + 16 + rsub + r) * ESTRIDE + nt * 16 + lrow] = acc1[nt][r] + bv[nt];
                }
            }
        }
        __syncthreads();
        // permuted copy: gather the 4 gate cols of unit u -> one coalesced float4
        for (int f = tid; f < 64 * 50; f += 256) {
            const int row = f / 50;
            const int u = f - row * 50;
            float4 v;
            v.x = elds[row * ESTRIDE + u];          // i
            v.y = elds[row * ESTRIDE + u + 50];     // f
            v.z = elds[row * ESTRIDE + u + 100];    // g
            v.w = elds[row * ESTRIDE + u + 150];    // o
            *(float4*)&zx[(rowbase + half * 64 + row) * ZN + u * 4] = v;
        }
    }
}

// ---------------- Kernel B: scan10 — BYTE-IDENTICAL to round-10 (483 us proven) --
#define ISSUE4(DST, T0) do {                                                  \
    _Pragma("unroll")                                                         \
    for (int s = 0; s < 4; ++s) {                                             \
        int tt = (T0) + s; if (tt > TT - 1) tt = TT - 1;                      \
        if (act) DST[s] = *(const float4*)&zp[(size_t)tt * ZN + l * 4];       \
    }                                                                         \
} while (0)

#define STEP9(V) do {                                                         \
    f32x2 acc0 = {(V).x, 0.f}, acc1 = {(V).y, 0.f};                           \
    f32x2 acc2 = {(V).z, 0.f}, acc3 = {(V).w, 0.f};                           \
    _Pragma("unroll")                                                         \
    for (int k4 = 0; k4 < 12; ++k4) {                                         \
        float4 hv = ((const float4*)hbuf)[k4];     /* uniform addr broadcast */ \
        f32x2 hp0 = {hv.x, hv.y}, hp1 = {hv.z, hv.w};                         \
        acc0 = __builtin_elementwise_fma(hp0, rr0[2 * k4], acc0);             \
        acc1 = __builtin_elementwise_fma(hp0, rr1[2 * k4], acc1);             \
        acc2 = __builtin_elementwise_fma(hp0, rr2[2 * k4], acc2);             \
        acc3 = __builtin_elementwise_fma(hp0, rr3[2 * k4], acc3);             \
        acc0 = __builtin_elementwise_fma(hp1, rr0[2 * k4 + 1], acc0);         \
        acc1 = __builtin_elementwise_fma(hp1, rr1[2 * k4 + 1], acc1);         \
        acc2 = __builtin_elementwise_fma(hp1, rr2[2 * k4 + 1], acc2);         \
        acc3 = __builtin_elementwise_fma(hp1, rr3[2 * k4 + 1], acc3);         \
    }                                                                         \
    {                                                                         \
        f32x2 hp = ((const f32x2*)hbuf)[24];       /* h[48], h[49] */         \
        acc0 = __builtin_elementwise_fma(hp, rr0[24], acc0);                  \
        acc1 = __builtin_elementwise_fma(hp, rr1[24], acc1);                  \
        acc2 = __builtin_elementwise_fma(hp, rr2[24], acc2);                  \
        acc3 = __builtin_elementwise_fma(hp, rr3[24], acc3);                  \
    }                                                                         \
    float zi = acc0.x + acc0.y, zf = acc1.x + acc1.y;                         \
    float zg = acc2.x + acc2.y, zo = acc3.x + acc3.y;                         \
    float gi = sigmoid_fast(zi), gf = sigmoid_fast(zf);                       \
    float go = sigmoid_fast(zo), gg = tanh_fast(zg);                          \
    c = gf * c + gi * gg;                                                     \
    h = go * tanh_fast(c);                                                    \
    hbuf[l] = h;                                                              \
} while (0)

#define STEPS4(SRC) do {                                                      \
    STEP9(SRC[0]); STEP9(SRC[1]); STEP9(SRC[2]); STEP9(SRC[3]);               \
} while (0)

__launch_bounds__(64, 1)
__global__ void lstm_scan10_kernel(const float* __restrict__ zx4,
                                   const float* __restrict__ R,
                                   const float* __restrict__ dw,
                                   const float* __restrict__ db,
                                   float* __restrict__ out) {
    const int l = threadIdx.x;
    const int b = blockIdx.x;
    const bool act = (l < UU);

    __shared__ __align__(16) float hbuf[64];

    f32x2 rr0[25], rr1[25], rr2[25], rr3[25];
    #pragma unroll
    for (int p = 0; p < 25; ++p) {
        if (act) {
            rr0[p] = (f32x2){ R[(2 * p) * ZN + l],       R[(2 * p + 1) * ZN + l] };
            rr1[p] = (f32x2){ R[(2 * p) * ZN + l + 50],  R[(2 * p + 1) * ZN + l + 50] };
            rr2[p] = (f32x2){ R[(2 * p) * ZN + l + 100], R[(2 * p + 1) * ZN + l + 100] };
            rr3[p] = (f32x2){ R[(2 * p) * ZN + l + 150], R[(2 * p + 1) * ZN + l + 150] };
        } else {
            rr0[p] = (f32x2){0.f, 0.f}; rr1[p] = (f32x2){0.f, 0.f};
            rr2[p] = (f32x2){0.f, 0.f}; rr3[p] = (f32x2){0.f, 0.f};
        }
    }
    #pragma unroll
    for (int p = 0; p < 25; ++p)
        asm volatile("" : "+v"(rr0[p]), "+v"(rr1[p]), "+v"(rr2[p]), "+v"(rr3[p]));

    const float dwv = act ? dw[l] : 0.0f;
    const float* zp = zx4 + (size_t)b * TT * ZN;

    hbuf[l] = 0.0f;
    float h = 0.0f, c = 0.0f;

    float4 pf[4], qf[4];
    #pragma unroll
    for (int s = 0; s < 4; ++s) { pf[s] = (float4){0,0,0,0}; qf[s] = (float4){0,0,0,0}; }

    ISSUE4(pf, 0);
    for (int t = 0; t < TT; t += 8) {
        ISSUE4(qf, t + 4);
        STEPS4(pf);                      // steps t .. t+3
        ISSUE4(pf, t + 8);               // clamped (dead) on last iteration
        STEPS4(qf);                      // steps t+4 .. t+7
    }

    float s = act ? h * dwv : 0.0f;
    #pragma unroll
    for (int off = 32; off > 0; off >>= 1) s += __shfl_down(s, off, 64);
    if (l == 0) out[b] = s + db[0];
}

// ---------------- Fallback GEMM (permuted store) ---------------------------------
__launch_bounds__(256, 1)
__global__ void xk_gemm_kernel(const float* __restrict__ x,
                               const float* __restrict__ K,
                               const float* __restrict__ bias,
                               float* __restrict__ zx) {
    const int b = blockIdx.x;
    const int j = threadIdx.x;

    __shared__ __align__(16) float xs[2][RPP * FF];

    float kreg[FF];
    float bj = 0.0f;
    if (j < ZN) {
        #pragma unroll
        for (int k = 0; k < FF; ++k) kreg[k] = K[k * ZN + j];
        bj = bias[j];
    }
    const int jpos = (j % UU) * 4 + (j / UU);

    const float* xrow = x + (size_t)b * TT * FF;
    float* zrow = zx + (size_t)b * TT * ZN;

    ((float4*)xs[0])[threadIdx.x] = ((const float4*)xrow)[threadIdx.x];
    __syncthreads();

    const int NPASS = TT / RPP;
    for (int p = 0; p < NPASS; ++p) {
        const int cur = p & 1, nxt = cur ^ 1;
        float4 gxv;
        const bool more = (p + 1) < NPASS;
        if (more) gxv = ((const float4*)(xrow + (size_t)(p + 1) * RPP * FF))[threadIdx.x];

        if (j < ZN) {
            float acc[RPP];
            #pragma unroll
            for (int r = 0; r < RPP; ++r) acc[r] = bj;
            const float4* xb4 = (const float4*)xs[cur];
            #pragma unroll
            for (int k4 = 0; k4 < FF / 4; ++k4) {
                #pragma unroll
                for (int r = 0; r < RPP; ++r) {
                    float4 xv = xb4[r * (FF / 4) + k4];
                    acc[r] = fmaf(xv.x, kreg[4 * k4 + 0], acc[r]);
                    acc[r] = fmaf(xv.y, kreg[4 * k4 + 1], acc[r]);
                    acc[r] = fmaf(xv.z, kreg[4 * k4 + 2], acc[r]);
                    acc[r] = fmaf(xv.w, kreg[4 * k4 + 3], acc[r]);
                }
            }
            float* zpo = zrow + (size_t)p * RPP * ZN + jpos;
            #pragma unroll
            for (int r = 0; r < RPP; ++r) zpo[r * ZN] = acc[r];
        }
        if (more) ((float4*)xs[nxt])[threadIdx.x] = gxv;
        __syncthreads();
    }
}

extern "C" void kernel_launch(void* const* d_in, const int* in_sizes, int n_in,
                              void* d_out, int out_size, void* d_ws, size_t ws_size,
                              hipStream_t stream) {
    const float* x    = (const float*)d_in[0];  // [512,1024,128]
    const float* K    = (const float*)d_in[1];  // [128,200]
    const float* R    = (const float*)d_in[2];  // [50,200]
    const float* bias = (const float*)d_in[3];  // [200]
    const float* dw   = (const float*)d_in[4];  // [50,1]
    const float* db   = (const float*)d_in[5];  // [1]
    float* out = (float*)d_out;                 // [512,1]

    const size_t zx_bytes = (size_t)MROWS * ZN * sizeof(float);          // 419.43 MB
    const size_t kt_elems = (size_t)NP * FF;
    const size_t kt_bytes = kt_elems * sizeof(unsigned short);

    if (ws_size >= zx_bytes + 2 * kt_bytes) {
        float* zx = (float*)d_ws;
        unsigned short* kt_hi = (unsigned short*)((char*)d_ws + zx_bytes);
        unsigned short* kt_lo = kt_hi + kt_elems;
        prep_kt_kernel<<<(NP * FF + 255) / 256, 256, 0, stream>>>(K, kt_hi, kt_lo);
        xk_mfma_kernel<<<MROWS / BM, 256, 0, stream>>>(x, kt_hi, kt_lo, bias, zx);
        lstm_scan10_kernel<<<BATCH, 64, 0, stream>>>(zx, R, dw, db, out);
    } else if (ws_size >= zx_bytes) {
        float* zx = (float*)d_ws;
        xk_gemm_kernel<<<BATCH, 256, 0, stream>>>(x, K, bias, zx);
        lstm_scan10_kernel<<<BATCH, 64, 0, stream>>>(zx, R, dw, db, out);
    }
}